// Round 1
// baseline (286.124 us; speedup 1.0000x reference)
//
#include <hip/hip_runtime.h>
#include <stdint.h>

#define HH 128
typedef unsigned long long ull;

__device__ __forceinline__ ull shfl_up64(ull v, int d) {
  unsigned lo = (unsigned)__shfl_up((int)(unsigned)(v & 0xffffffffULL), d);
  unsigned hi = (unsigned)__shfl_up((int)(unsigned)(v >> 32), d);
  return ((ull)hi << 32) | (ull)lo;
}

__device__ __forceinline__ void fma4(float4& a, float s, const float4& w) {
  a.x = fmaf(s, w.x, a.x); a.y = fmaf(s, w.y, a.y);
  a.z = fmaf(s, w.z, a.z); a.w = fmaf(s, w.w, a.w);
}

// ---- transpose 6 weight matrices into WT: WlT2, WrT2, WlT3, WrT3, W0T, W1T ----
__global__ void k_transpose(const float* __restrict__ Wl, const float* __restrict__ Wr,
                            const float* __restrict__ W0, const float* __restrict__ W1,
                            float* __restrict__ WT) {
  int gid = blockIdx.x * blockDim.x + threadIdx.x;
  if (gid >= 6 * HH * HH) return;
  int m = gid / (HH * HH);
  int idx = gid % (HH * HH);
  int k = idx / HH, j = idx % HH;
  const float* src;
  switch (m) {
    case 0: src = Wl + 1 * HH * HH; break;
    case 1: src = Wr + 1 * HH * HH; break;
    case 2: src = Wl + 2 * HH * HH; break;
    case 3: src = Wr + 2 * HH * HH; break;
    case 4: src = W0; break;
    default: src = W1; break;
  }
  WT[gid] = src[j * HH + k];
}

// ---- A0,A1,R0,R1 vectors for the layer-1 counting trick ----
__global__ void k_vecs(const float* __restrict__ zt, const float* __restrict__ Wl0,
                       const float* __restrict__ Wr0, float* __restrict__ vecs) {
  int j = threadIdx.x;
  if (j >= HH) return;
  float a0 = 0, a1 = 0, r0 = 0, r1 = 0;
  for (int k = 0; k < HH; k++) {
    float z0 = zt[k], z1 = zt[HH + k];
    float wl = Wl0[j * HH + k], wr = Wr0[j * HH + k];
    a0 += z0 * wl; a1 += z1 * wl; r0 += z0 * wr; r1 += z1 * wr;
  }
  vecs[j] = a0; vecs[HH + j] = a1; vecs[2 * HH + j] = r0; vecs[3 * HH + j] = r1;
}

// ---- edge pass: degree, per-channel label counts, mark set ----
__global__ void k_edge(const int* __restrict__ z, const int* __restrict__ src,
                       const int* __restrict__ dst, int N, int E,
                       int* __restrict__ deg, int* __restrict__ cnt, int* __restrict__ mark) {
  int tid = blockIdx.x * blockDim.x + threadIdx.x;
  int stride = gridDim.x * blockDim.x;
  for (int n = tid; n < N; n += stride)
    if (z[n] <= 2) mark[n] = 1;
  for (int e = tid; e < E; e += stride) {
    int s = src[e], d = dst[e];
    atomicAdd(&deg[d], 1);
    int zs = z[s];
    if (zs == 1) atomicAdd(&cnt[d], 1);
    else if (zs == 2) atomicAdd(&cnt[N + d], 1);
    if (z[d] <= 2) mark[s] = 1;
  }
}

// ---- packed 64-bit scan: deg(0..19) | mark(20..39) | z==1(40..51) | z==2(52..63) ----
__global__ void k_scan1(const int* __restrict__ deg, const int* __restrict__ mark,
                        const int* __restrict__ z, int N,
                        ull* __restrict__ locout, ull* __restrict__ partials) {
  __shared__ ull wsum[4];
  int t = threadIdx.x, b = blockIdx.x;
  int base = b * 1024 + t * 4;
  ull l[4]; ull s = 0;
  for (int i = 0; i < 4; i++) {
    int idx = base + i; ull v = 0;
    if (idx < N) {
      int zz = z[idx];
      v = (ull)deg[idx] | ((ull)mark[idx] << 20)
        | ((ull)(zz == 1) << 40) | ((ull)(zz == 2) << 52);
    }
    l[i] = s; s += v;
  }
  int lane = t & 63, wid = t >> 6;
  ull vi = s;
  for (int d2 = 1; d2 < 64; d2 <<= 1) { ull o = shfl_up64(vi, d2); if (lane >= d2) vi += o; }
  if (lane == 63) wsum[wid] = vi;
  __syncthreads();
  ull woff = 0;
  for (int w = 0; w < wid; w++) woff += wsum[w];
  ull thrbase = woff + vi - s;
  for (int i = 0; i < 4; i++) {
    int idx = base + i;
    if (idx < N) locout[idx] = thrbase + l[i];
  }
  if (t == 255) partials[b] = woff + vi;
}

__global__ void k_scan2(ull* __restrict__ partials, int nb) {
  int lane = threadIdx.x;
  ull v = (lane < nb) ? partials[lane] : 0;
  ull vi = v;
  for (int d2 = 1; d2 < 64; d2 <<= 1) { ull o = shfl_up64(vi, d2); if (lane >= d2) vi += o; }
  if (lane < nb) partials[lane] = vi - v;
}

// ---- consume scan: rowptr, mlist (compacted marked), plist (ordered z==1 then z==2) ----
__global__ void k_post(const ull* __restrict__ locout, const ull* __restrict__ partials,
                       const int* __restrict__ z, const int* __restrict__ mark,
                       int N, int P, int* __restrict__ rowptr, int* __restrict__ mlist,
                       int* __restrict__ plist, int* __restrict__ Rm) {
  int n = blockIdx.x * blockDim.x + threadIdx.x;
  if (n >= N) return;
  ull s = locout[n] + partials[n >> 10];
  int rp = (int)(s & 0xFFFFF);
  int mp = (int)((s >> 20) & 0xFFFFF);
  int r1 = (int)((s >> 40) & 0xFFF);
  int r2 = (int)(s >> 52);
  rowptr[n] = rp;
  if (mark[n]) mlist[mp] = n;
  int zz = z[n];
  if (zz == 1) plist[r1] = n;
  else if (zz == 2) plist[P + r2] = n;
  if (n == N - 1) *Rm = mp + mark[n];
}

__global__ void k_csr(const int* __restrict__ src, const int* __restrict__ dst, int E,
                      const int* __restrict__ rowptr, int* __restrict__ cursor,
                      int* __restrict__ csr_src) {
  int e = blockIdx.x * blockDim.x + threadIdx.x;
  if (e >= E) return;
  int d = dst[e];
  int pos = atomicAdd(&cursor[d], 1);
  csr_src[rowptr[d] + pos] = src[e];
}

// ---- layer-1 output via counting trick (elementwise, no gather/GEMM) ----
__global__ void k_x1(const int* __restrict__ z, const int* __restrict__ deg,
                     const int* __restrict__ cnt, const float* __restrict__ vecs,
                     const float* __restrict__ bl0, int N, float* __restrict__ x1) {
  int t = threadIdx.x;
  int n = blockIdx.x * 4 + (t >> 6);
  if (n >= N) return;
  int j = (t & 63) * 2;
  int d = deg[n];
  float invd = 1.0f / (float)max(d, 1);
  int zz = z[n];
  float2 A0 = *(const float2*)(vecs + j);
  float2 A1 = *(const float2*)(vecs + HH + j);
  float2 R0 = *(const float2*)(vecs + 2 * HH + j);
  float2 R1 = *(const float2*)(vecs + 3 * HH + j);
  float2 bb = *(const float2*)(bl0 + j);
  for (int c = 0; c < 2; c++) {
    int c1 = cnt[c * N + n];
    float u1 = (float)c1 * invd;
    float u0 = (float)(d - c1) * invd;
    float2 R = (zz == c + 1) ? R1 : R0;
    float vx = fmaxf(u0 * A0.x + u1 * A1.x + bb.x + R.x, 0.f);
    float vy = fmaxf(u0 * A0.y + u1 * A1.y + bb.y + R.y, 0.f);
    float2 o; o.x = vx; o.y = vy;
    *(float2*)(x1 + ((size_t)c * N + n) * HH + j) = o;
  }
}

// ---- CSR mean-aggregate; one wave per (channel, task). COMPACT: output compact rows ----
template<int COMPACT>
__global__ __launch_bounds__(256) void k_agg(const float* __restrict__ xin, float* __restrict__ out,
                      const int* __restrict__ tasklist, const int* __restrict__ Rdev, int staticT,
                      const int* __restrict__ rowptr, const int* __restrict__ deg,
                      const int* __restrict__ csr_src, int N, int P2) {
  int gt = blockIdx.x * blockDim.x + threadIdx.x;
  int w = gt >> 6, lane = gt & 63;
  int nw = (gridDim.x * blockDim.x) >> 6;
  int T = (staticT >= 0) ? staticT : 2 * (*Rdev);
  int j = lane * 2;
  for (int task = w; task < T; task += nw) {
    int c = task & 1, m = task >> 1;
    int n = tasklist[m];
    int beg = rowptr[n], d = deg[n];
    float inv = 1.0f / (float)max(d, 1);
    const float* base = xin + (size_t)c * N * HH;
    float ax = 0.f, ay = 0.f;
    for (int i = 0; i < d; i++) {
      int s = csr_src[beg + i];
      float2 v = *(const float2*)(base + (size_t)s * HH + j);
      ax += v.x; ay += v.y;
    }
    float2 o; o.x = ax * inv; o.y = ay * inv;
    size_t orow = COMPACT ? ((size_t)c * P2 + m) : ((size_t)c * N + n);
    *(float2*)(out + orow * HH + j) = o;
  }
}

// ---- tiled fp32 GEMM over gathered rows: OUT = A@WaT + X@WxT + bias (opt. relu) ----
// MODE 0: layer2 rows (c=r&1, n=mlist[r>>1]), dual, relu
// MODE 1: layer3 rows (c=r/P2, i=r%P2, n=plist[i]), dual, no relu, compact A/out
// MODE 2: W0 stage, single matrix, compact in/out, relu
template<int MODE>
__global__ __launch_bounds__(256) void k_gemm(const float* __restrict__ Abase, const float* __restrict__ Xbase,
                       const float* __restrict__ WaT, const float* __restrict__ WxT,
                       const float* __restrict__ bias, float* __restrict__ Obase,
                       const int* __restrict__ mlist, const int* __restrict__ plist,
                       const int* __restrict__ Rdev, int N, int P2) {
  __shared__ float aS[HH][36];
  __shared__ float xS[HH][36];
  int R = (MODE == 0) ? 2 * (*Rdev) : 2 * P2;
  int ntiles = (R + 31) >> 5;
  for (int tile = blockIdx.x; tile < ntiles; tile += gridDim.x) {
    int r0 = tile << 5;
    int rr = threadIdx.x >> 3;
    int f = threadIdx.x & 7;
    int r = r0 + rr;
    const float *aRow = nullptr, *xRow = nullptr;
    bool valid = (r < R);
    if (valid) {
      if (MODE == 0) {
        int c = r & 1, m = r >> 1; int n = mlist[m];
        size_t o = ((size_t)c * N + n) * HH;
        aRow = Abase + ((size_t)c * N + n) * HH; xRow = Xbase + o;
      } else if (MODE == 1) {
        int c = r / P2, i = r % P2; int n = plist[i];
        aRow = Abase + ((size_t)c * P2 + i) * HH;
        xRow = Xbase + ((size_t)c * N + n) * HH;
      } else {
        xRow = Xbase + (size_t)r * HH;
      }
    }
#pragma unroll
    for (int rep = 0; rep < 4; rep++) {
      int k0 = f * 4 + rep * 32;
      float4 xv = valid ? *(const float4*)(xRow + k0) : make_float4(0, 0, 0, 0);
      xS[k0 + 0][rr] = xv.x; xS[k0 + 1][rr] = xv.y; xS[k0 + 2][rr] = xv.z; xS[k0 + 3][rr] = xv.w;
      if (MODE != 2) {
        float4 av = valid ? *(const float4*)(aRow + k0) : make_float4(0, 0, 0, 0);
        aS[k0 + 0][rr] = av.x; aS[k0 + 1][rr] = av.y; aS[k0 + 2][rr] = av.z; aS[k0 + 3][rr] = av.w;
      }
    }
    __syncthreads();
    int jg = threadIdx.x & 31, rg = threadIdx.x >> 5;
    int j0 = jg * 4;
    float4 acc[4];
    acc[0] = acc[1] = acc[2] = acc[3] = make_float4(0, 0, 0, 0);
#pragma unroll 4
    for (int k = 0; k < HH; k++) {
      float4 wx = *(const float4*)(WxT + k * HH + j0);
      float4 xv = *(const float4*)(&xS[k][rg * 4]);
      fma4(acc[0], xv.x, wx); fma4(acc[1], xv.y, wx);
      fma4(acc[2], xv.z, wx); fma4(acc[3], xv.w, wx);
      if (MODE != 2) {
        float4 wa = *(const float4*)(WaT + k * HH + j0);
        float4 av = *(const float4*)(&aS[k][rg * 4]);
        fma4(acc[0], av.x, wa); fma4(acc[1], av.y, wa);
        fma4(acc[2], av.z, wa); fma4(acc[3], av.w, wa);
      }
    }
    float4 b4 = *(const float4*)(bias + j0);
#pragma unroll
    for (int q = 0; q < 4; q++) {
      int rq = r0 + rg * 4 + q;
      if (rq < R) {
        float4 v = acc[q];
        v.x += b4.x; v.y += b4.y; v.z += b4.z; v.w += b4.w;
        if (MODE == 0 || MODE == 2) {
          v.x = fmaxf(v.x, 0.f); v.y = fmaxf(v.y, 0.f);
          v.z = fmaxf(v.z, 0.f); v.w = fmaxf(v.w, 0.f);
        }
        float* orow;
        if (MODE == 0) {
          int c = rq & 1, m = rq >> 1; int n = mlist[m];
          orow = Obase + ((size_t)c * N + n) * HH;
        } else {
          orow = Obase + (size_t)rq * HH;
        }
        *(float4*)(orow + j0) = v;
      }
    }
    __syncthreads();
  }
}

// ---- h = sum over channels, p = h[src]*h[dst] ----
__global__ void k_pair(const float* __restrict__ tmp0, int P, int P2, float* __restrict__ p) {
  int tid = blockIdx.x * blockDim.x + threadIdx.x;
  int total = P * (HH / 4);
  if (tid >= total) return;
  int i = tid / (HH / 4);
  int jq = tid % (HH / 4);
  int j0 = jq * 4;
  float4 a0 = *(const float4*)(tmp0 + ((size_t)0 * P2 + i) * HH + j0);
  float4 a1 = *(const float4*)(tmp0 + ((size_t)1 * P2 + i) * HH + j0);
  float4 d0 = *(const float4*)(tmp0 + ((size_t)0 * P2 + i + P) * HH + j0);
  float4 d1 = *(const float4*)(tmp0 + ((size_t)1 * P2 + i + P) * HH + j0);
  float4 o;
  o.x = (a0.x + a1.x) * (d0.x + d1.x);
  o.y = (a0.y + a1.y) * (d0.y + d1.y);
  o.z = (a0.z + a1.z) * (d0.z + d1.z);
  o.w = (a0.w + a1.w) * (d0.w + d1.w);
  *(float4*)(p + (size_t)i * HH + j0) = o;
}

// ---- final MLP: out[i] = relu(p_i @ W1T + b1) @ W2 + b2 ----
__global__ void k_final(const float* __restrict__ p, const float* __restrict__ W1T,
                        const float* __restrict__ b1, const float* __restrict__ W2,
                        const float* __restrict__ b2, int P, float* __restrict__ out) {
  __shared__ float pS[2][HH];
  __shared__ float wred[4];
  int t = threadIdx.x;
  int half = t >> 7, j = t & 127;
  int i = blockIdx.x * 2 + half;
  pS[half][j] = p[(size_t)i * HH + j];
  __syncthreads();
  float acc = b1[j];
#pragma unroll 8
  for (int k = 0; k < HH; k++) acc += pS[half][k] * W1T[k * HH + j];
  float v = fmaxf(acc, 0.f) * W2[j];
  for (int off = 32; off > 0; off >>= 1) v += __shfl_down(v, off);
  int wid = t >> 6, lane = t & 63;
  if (lane == 0) wred[wid] = v;
  __syncthreads();
  if (t == 0) out[i] = wred[0] + wred[1] + b2[0];
  else if (t == 128) out[i] = wred[2] + wred[3] + b2[0];
}

extern "C" void kernel_launch(void* const* d_in, const int* in_sizes, int n_in,
                              void* d_out, int out_size, void* d_ws, size_t ws_size,
                              hipStream_t stream) {
  const int* z = (const int*)d_in[0];
  const int* ei = (const int*)d_in[1];
  const float* z_table = (const float*)d_in[3];
  const float* conv_Wl = (const float*)d_in[4];
  const float* conv_bl = (const float*)d_in[5];
  const float* conv_Wr = (const float*)d_in[6];
  const float* W0 = (const float*)d_in[7];
  const float* b0 = (const float*)d_in[8];
  const float* W1 = (const float*)d_in[9];
  const float* b1 = (const float*)d_in[10];
  const float* W2 = (const float*)d_in[11];
  const float* b2 = (const float*)d_in[12];
  float* out = (float*)d_out;

  int N = in_sizes[0];
  int E = in_sizes[1] / 2;
  int P = out_size;
  int P2 = 2 * P;
  const int* srcA = ei;
  const int* dstA = ei + E;

  char* basep = (char*)d_ws;
  size_t off = 0;
  auto alloc = [&](size_t bytes) -> char* {
    off = (off + 255) & ~(size_t)255;
    char* pp = basep + off; off += bytes; return pp;
  };
  float* x1 = (float*)alloc((size_t)2 * N * HH * 4);
  float* x2 = (float*)alloc((size_t)2 * N * HH * 4);
  float* agg = (float*)alloc((size_t)2 * N * HH * 4);
  float* aggp = (float*)alloc((size_t)2 * P2 * HH * 4);
  float* x3 = (float*)alloc((size_t)2 * P2 * HH * 4);
  float* tmp0 = (float*)alloc((size_t)2 * P2 * HH * 4);
  float* pbuf = (float*)alloc((size_t)P * HH * 4);
  float* WT = (float*)alloc((size_t)6 * HH * HH * 4);
  float* vecs = (float*)alloc((size_t)4 * HH * 4);
  int* zero_region = (int*)alloc((size_t)5 * N * 4);
  int* deg = zero_region;
  int* cnt = zero_region + N;
  int* mark = zero_region + 3 * (size_t)N;
  int* cursor = zero_region + 4 * (size_t)N;
  int* rowptr = (int*)alloc((size_t)N * 4);
  int* mlist = (int*)alloc((size_t)N * 4);
  int* plist = (int*)alloc((size_t)P2 * 4);
  int* csr = (int*)alloc((size_t)E * 4);
  ull* locout = (ull*)alloc((size_t)N * 8);
  ull* partials = (ull*)alloc(64 * 8);
  int* Rm_dev = (int*)alloc(4);
  (void)ws_size; (void)n_in;

  hipMemsetAsync(zero_region, 0, (size_t)5 * N * 4, stream);
  k_transpose<<<(6 * HH * HH + 255) / 256, 256, 0, stream>>>(conv_Wl, conv_Wr, W0, W1, WT);
  k_vecs<<<1, HH, 0, stream>>>(z_table, conv_Wl, conv_Wr, vecs);
  k_edge<<<2048, 256, 0, stream>>>(z, srcA, dstA, N, E, deg, cnt, mark);
  int nb = (N + 1023) / 1024;
  k_scan1<<<nb, 256, 0, stream>>>(deg, mark, z, N, locout, partials);
  k_scan2<<<1, 64, 0, stream>>>(partials, nb);
  k_post<<<(N + 255) / 256, 256, 0, stream>>>(locout, partials, z, mark, N, P, rowptr, mlist, plist, Rm_dev);
  k_csr<<<(E + 255) / 256, 256, 0, stream>>>(srcA, dstA, E, rowptr, cursor, csr);
  k_x1<<<(N + 3) / 4, 256, 0, stream>>>(z, deg, cnt, vecs, conv_bl, N, x1);
  // layer 2 (marked nodes only)
  k_agg<0><<<1024, 256, 0, stream>>>(x1, agg, mlist, Rm_dev, -1, rowptr, deg, csr, N, P2);
  k_gemm<0><<<1024, 256, 0, stream>>>(agg, x1, WT, WT + HH * HH, conv_bl + HH, x2, mlist, plist, Rm_dev, N, P2);
  // layer 3 (pair nodes only)
  k_agg<1><<<256, 256, 0, stream>>>(x2, aggp, plist, Rm_dev, 2 * P2, rowptr, deg, csr, N, P2);
  k_gemm<1><<<128, 256, 0, stream>>>(aggp, x2, WT + 2 * HH * HH, WT + 3 * HH * HH, conv_bl + 2 * HH, x3, mlist, plist, Rm_dev, N, P2);
  // W0 stage
  k_gemm<2><<<128, 256, 0, stream>>>(nullptr, x3, nullptr, WT + 4 * HH * HH, b0, tmp0, mlist, plist, Rm_dev, N, P2);
  // pair products + final MLP
  k_pair<<<(P * (HH / 4) + 255) / 256, 256, 0, stream>>>(tmp0, P, P2, pbuf);
  k_final<<<P / 2, 256, 0, stream>>>(pbuf, WT + 5 * HH * HH, b1, W2, b2, P, out);
}

// Round 2
// 236.415 us; speedup vs baseline: 1.2103x; 1.2103x over previous
//
#include <hip/hip_runtime.h>
#include <stdint.h>

#define HH 128
typedef unsigned long long ull;

__device__ __forceinline__ ull shfl_up64(ull v, int d) {
  unsigned lo = (unsigned)__shfl_up((int)(unsigned)(v & 0xffffffffULL), d);
  unsigned hi = (unsigned)__shfl_up((int)(unsigned)(v >> 32), d);
  return ((ull)hi << 32) | (ull)lo;
}
__device__ __forceinline__ ull shfl_down64(ull v, int d) {
  unsigned lo = (unsigned)__shfl_down((int)(unsigned)(v & 0xffffffffULL), d);
  unsigned hi = (unsigned)__shfl_down((int)(unsigned)(v >> 32), d);
  return ((ull)hi << 32) | (ull)lo;
}
__device__ __forceinline__ void fma4(float4& a, float s, const float4& w) {
  a.x = fmaf(s, w.x, a.x); a.y = fmaf(s, w.y, a.y);
  a.z = fmaf(s, w.z, a.z); a.w = fmaf(s, w.w, a.w);
}

// ---- weights transpose (6 mats) + layer-1 basis vectors, one launch ----
__global__ void k_prep(const float* __restrict__ Wl, const float* __restrict__ Wr,
                       const float* __restrict__ W0, const float* __restrict__ W1,
                       const float* __restrict__ zt, float* __restrict__ WT,
                       float* __restrict__ vecs, int nTblk) {
  if ((int)blockIdx.x == nTblk) {
    int j = threadIdx.x;
    if (j >= HH) return;
    float a0 = 0, a1 = 0, r0 = 0, r1 = 0;
    for (int k = 0; k < HH; k++) {
      float z0 = zt[k], z1 = zt[HH + k];
      float wl = Wl[j * HH + k], wr = Wr[j * HH + k];
      a0 += z0 * wl; a1 += z1 * wl; r0 += z0 * wr; r1 += z1 * wr;
    }
    vecs[j] = a0; vecs[HH + j] = a1; vecs[2 * HH + j] = r0; vecs[3 * HH + j] = r1;
    return;
  }
  int gid = blockIdx.x * blockDim.x + threadIdx.x;
  if (gid >= 6 * HH * HH) return;
  int m = gid / (HH * HH);
  int idx = gid % (HH * HH);
  int k = idx / HH, j = idx % HH;
  const float* src;
  switch (m) {
    case 0: src = Wl + 1 * HH * HH; break;   // WlT2
    case 1: src = Wr + 1 * HH * HH; break;   // WrT2
    case 2: src = Wl + 2 * HH * HH; break;   // WlT3
    case 3: src = Wr + 2 * HH * HH; break;   // WrT3
    case 4: src = W0; break;                 // W0T
    default: src = W1; break;                // W1T
  }
  WT[gid] = src[j * HH + k];
}

// ---- edge pass: degree, per-channel label counts, mark set ----
__global__ void k_edge(const int* __restrict__ z, const int* __restrict__ src,
                       const int* __restrict__ dst, int N, int E,
                       int* __restrict__ deg, int* __restrict__ cnt, int* __restrict__ mark) {
  int tid = blockIdx.x * blockDim.x + threadIdx.x;
  int stride = gridDim.x * blockDim.x;
  for (int n = tid; n < N; n += stride)
    if (z[n] <= 2) mark[n] = 1;
  for (int e = tid; e < E; e += stride) {
    int s = src[e], d = dst[e];
    atomicAdd(&deg[d], 1);
    int zs = z[s];
    if (zs == 1) atomicAdd(&cnt[d], 1);
    else if (zs == 2) atomicAdd(&cnt[N + d], 1);
    if (z[d] <= 2) mark[s] = 1;
  }
}

// ---- packed 64-bit scan: deg(0..19) | mark(20..39) | z==1(40..51) | z==2(52..63) ----
__global__ void k_scan1(const int* __restrict__ deg, const int* __restrict__ mark,
                        const int* __restrict__ z, int N,
                        ull* __restrict__ locout, ull* __restrict__ partials) {
  __shared__ ull wsum[4];
  int t = threadIdx.x, b = blockIdx.x;
  int base = b * 1024 + t * 4;
  ull l[4]; ull s = 0;
  for (int i = 0; i < 4; i++) {
    int idx = base + i; ull v = 0;
    if (idx < N) {
      int zz = z[idx];
      v = (ull)deg[idx] | ((ull)mark[idx] << 20)
        | ((ull)(zz == 1) << 40) | ((ull)(zz == 2) << 52);
    }
    l[i] = s; s += v;
  }
  int lane = t & 63, wid = t >> 6;
  ull vi = s;
  for (int d2 = 1; d2 < 64; d2 <<= 1) { ull o = shfl_up64(vi, d2); if (lane >= d2) vi += o; }
  if (lane == 63) wsum[wid] = vi;
  __syncthreads();
  ull woff = 0;
  for (int w = 0; w < wid; w++) woff += wsum[w];
  ull thrbase = woff + vi - s;
  for (int i = 0; i < 4; i++) {
    int idx = base + i;
    if (idx < N) locout[idx] = thrbase + l[i];
  }
  if (t == 255) partials[b] = woff + vi;
}

// ---- consume scan (block-local reduce of partials replaces scan2 kernel) ----
__global__ __launch_bounds__(256) void k_post(const ull* __restrict__ locout, const ull* __restrict__ partials,
                       const int* __restrict__ z, const int* __restrict__ mark,
                       const int* __restrict__ deg, const int* __restrict__ cnt,
                       int N, int P, int* __restrict__ rowptr, int* __restrict__ mlist,
                       int* __restrict__ plist, int* __restrict__ Rm, int4* __restrict__ pack) {
  __shared__ ull base_s;
  int t = threadIdx.x;
  if (t < 64) {
    int need = blockIdx.x >> 2;   // chunk index = (block*256)>>10
    ull v = (t < need) ? partials[t] : 0ULL;
    for (int o = 32; o > 0; o >>= 1) v += shfl_down64(v, o);
    if (t == 0) base_s = v;
  }
  __syncthreads();
  int n = blockIdx.x * 256 + t;
  if (n >= N) return;
  ull s = locout[n] + base_s;
  int rp = (int)(s & 0xFFFFF);
  int mp = (int)((s >> 20) & 0xFFFFF);
  int r1 = (int)((s >> 40) & 0xFFF);
  int r2 = (int)(s >> 52);
  rowptr[n] = rp;
  if (mark[n]) mlist[mp] = n;
  int zz = z[n];
  if (zz == 1) plist[r1] = n;
  else if (zz == 2) plist[P + r2] = n;
  pack[n] = make_int4(deg[n], cnt[n], cnt[N + n], zz);
  if (n == N - 1) *Rm = mp + mark[n];
}

__global__ void k_csr(const int* __restrict__ src, const int* __restrict__ dst, int E,
                      const int* __restrict__ rowptr, int* __restrict__ cursor,
                      int* __restrict__ csr_src) {
  int e = blockIdx.x * blockDim.x + threadIdx.x;
  if (e >= E) return;
  int d = dst[e];
  int pos = atomicAdd(&cursor[d], 1);
  csr_src[rowptr[d] + pos] = src[e];
}

// ---- layer-2 aggregate with ON-THE-FLY x1 (16B pack load per neighbor) ----
__global__ __launch_bounds__(256) void k_agg2(const int4* __restrict__ pack,
    const float* __restrict__ vecs, const float* __restrict__ bl0,
    const int* __restrict__ csr, const int* __restrict__ rowptr,
    const int* __restrict__ mlist, const int* __restrict__ Rdev,
    float* __restrict__ agg) {
  int gt = blockIdx.x * blockDim.x + threadIdx.x;
  int w = gt >> 6, lane = gt & 63;
  int nw = (gridDim.x * blockDim.x) >> 6;
  int T = *Rdev;
  int ch = lane >> 5;
  int jj = (lane & 31) * 4;
  float4 A0 = *(const float4*)(vecs + jj);
  float4 A1 = *(const float4*)(vecs + HH + jj);
  float4 R0 = *(const float4*)(vecs + 2 * HH + jj);
  float4 R1 = *(const float4*)(vecs + 3 * HH + jj);
  float4 bb = *(const float4*)(bl0 + jj);
  float4 B0 = make_float4(bb.x + R0.x, bb.y + R0.y, bb.z + R0.z, bb.w + R0.w);
  float4 B1 = make_float4(bb.x + R1.x, bb.y + R1.y, bb.z + R1.z, bb.w + R1.w);
  int zc = ch + 1;
  for (int task = w; task < T; task += nw) {
    int n = mlist[task];
    int beg = rowptr[n];
    int d = pack[n].x;
    float4 acc = make_float4(0, 0, 0, 0);
    int i = 0;
    for (; i + 2 <= d; i += 2) {
      int s0 = csr[beg + i], s1 = csr[beg + i + 1];
      int4 p0 = pack[s0]; int4 p1 = pack[s1];
      {
        float invd = 1.0f / (float)max(p0.x, 1);
        int cc = ch ? p0.z : p0.y;
        float u1 = (float)cc * invd, u0 = (float)(p0.x - cc) * invd;
        float4 B = (p0.w == zc) ? B1 : B0;
        acc.x += fmaxf(fmaf(u0, A0.x, fmaf(u1, A1.x, B.x)), 0.f);
        acc.y += fmaxf(fmaf(u0, A0.y, fmaf(u1, A1.y, B.y)), 0.f);
        acc.z += fmaxf(fmaf(u0, A0.z, fmaf(u1, A1.z, B.z)), 0.f);
        acc.w += fmaxf(fmaf(u0, A0.w, fmaf(u1, A1.w, B.w)), 0.f);
      }
      {
        float invd = 1.0f / (float)max(p1.x, 1);
        int cc = ch ? p1.z : p1.y;
        float u1 = (float)cc * invd, u0 = (float)(p1.x - cc) * invd;
        float4 B = (p1.w == zc) ? B1 : B0;
        acc.x += fmaxf(fmaf(u0, A0.x, fmaf(u1, A1.x, B.x)), 0.f);
        acc.y += fmaxf(fmaf(u0, A0.y, fmaf(u1, A1.y, B.y)), 0.f);
        acc.z += fmaxf(fmaf(u0, A0.z, fmaf(u1, A1.z, B.z)), 0.f);
        acc.w += fmaxf(fmaf(u0, A0.w, fmaf(u1, A1.w, B.w)), 0.f);
      }
    }
    if (i < d) {
      int s0 = csr[beg + i];
      int4 p0 = pack[s0];
      float invd = 1.0f / (float)max(p0.x, 1);
      int cc = ch ? p0.z : p0.y;
      float u1 = (float)cc * invd, u0 = (float)(p0.x - cc) * invd;
      float4 B = (p0.w == zc) ? B1 : B0;
      acc.x += fmaxf(fmaf(u0, A0.x, fmaf(u1, A1.x, B.x)), 0.f);
      acc.y += fmaxf(fmaf(u0, A0.y, fmaf(u1, A1.y, B.y)), 0.f);
      acc.z += fmaxf(fmaf(u0, A0.z, fmaf(u1, A1.z, B.z)), 0.f);
      acc.w += fmaxf(fmaf(u0, A0.w, fmaf(u1, A1.w, B.w)), 0.f);
    }
    float inv = 1.0f / (float)max(d, 1);
    float4 o = make_float4(acc.x * inv, acc.y * inv, acc.z * inv, acc.w * inv);
    *(float4*)(agg + (size_t)task * (2 * HH) + lane * 4) = o;
  }
}

// ---- layer-2 GEMM: x2[n][c] = relu(agg@WlT2 + bl1 + x1(n,c)@WrT2), x1 on the fly ----
__global__ __launch_bounds__(256) void k_gemmL2(const float* __restrict__ Agg,
    const int4* __restrict__ pack, const float* __restrict__ vecs,
    const float* __restrict__ WaT, const float* __restrict__ WxT,
    const float* __restrict__ bias, const float* __restrict__ bl0,
    const int* __restrict__ mlist, const int* __restrict__ Rdev,
    float* __restrict__ x2) {
  __shared__ float aS[HH][36];
  __shared__ float xS[HH][36];
  int R = 2 * (*Rdev);
  int ntiles = (R + 31) >> 5;
  for (int tile = blockIdx.x; tile < ntiles; tile += gridDim.x) {
    int r0 = tile << 5;
    int rr = threadIdx.x >> 3, f = threadIdx.x & 7;
    int r = r0 + rr;
    bool valid = (r < R);
    int c = r & 1;
    int4 pk = make_int4(1, 0, 0, 0);
    if (valid) pk = pack[mlist[r >> 1]];
    const float* aRow = Agg + (size_t)r * HH;
    float invd = 1.0f / (float)max(pk.x, 1);
    int cc = c ? pk.z : pk.y;
    float u1 = (float)cc * invd, u0 = (float)(pk.x - cc) * invd;
    int sel = (pk.w == c + 1) ? 3 : 2;
#pragma unroll
    for (int rep = 0; rep < 4; rep++) {
      int k0 = f * 4 + rep * 32;
      float4 av = valid ? *(const float4*)(aRow + k0) : make_float4(0, 0, 0, 0);
      aS[k0 + 0][rr] = av.x; aS[k0 + 1][rr] = av.y; aS[k0 + 2][rr] = av.z; aS[k0 + 3][rr] = av.w;
      float4 A0 = *(const float4*)(vecs + k0);
      float4 A1 = *(const float4*)(vecs + HH + k0);
      float4 Rv = *(const float4*)(vecs + sel * HH + k0);
      float4 bv = *(const float4*)(bl0 + k0);
      float4 xv;
      xv.x = fmaxf(fmaf(u0, A0.x, fmaf(u1, A1.x, bv.x + Rv.x)), 0.f);
      xv.y = fmaxf(fmaf(u0, A0.y, fmaf(u1, A1.y, bv.y + Rv.y)), 0.f);
      xv.z = fmaxf(fmaf(u0, A0.z, fmaf(u1, A1.z, bv.z + Rv.z)), 0.f);
      xv.w = fmaxf(fmaf(u0, A0.w, fmaf(u1, A1.w, bv.w + Rv.w)), 0.f);
      if (!valid) xv = make_float4(0, 0, 0, 0);
      xS[k0 + 0][rr] = xv.x; xS[k0 + 1][rr] = xv.y; xS[k0 + 2][rr] = xv.z; xS[k0 + 3][rr] = xv.w;
    }
    __syncthreads();
    int jg = threadIdx.x & 31, rg = threadIdx.x >> 5;
    int j0 = jg * 4;
    float4 acc[4];
    acc[0] = acc[1] = acc[2] = acc[3] = make_float4(0, 0, 0, 0);
#pragma unroll 4
    for (int k = 0; k < HH; k++) {
      float4 wx = *(const float4*)(WxT + k * HH + j0);
      float4 xv = *(const float4*)(&xS[k][rg * 4]);
      fma4(acc[0], xv.x, wx); fma4(acc[1], xv.y, wx);
      fma4(acc[2], xv.z, wx); fma4(acc[3], xv.w, wx);
      float4 wa = *(const float4*)(WaT + k * HH + j0);
      float4 av = *(const float4*)(&aS[k][rg * 4]);
      fma4(acc[0], av.x, wa); fma4(acc[1], av.y, wa);
      fma4(acc[2], av.z, wa); fma4(acc[3], av.w, wa);
    }
    float4 b4 = *(const float4*)(bias + j0);
#pragma unroll
    for (int q = 0; q < 4; q++) {
      int rq = r0 + rg * 4 + q;
      if (rq < R) {
        float4 v = acc[q];
        v.x = fmaxf(v.x + b4.x, 0.f); v.y = fmaxf(v.y + b4.y, 0.f);
        v.z = fmaxf(v.z + b4.z, 0.f); v.w = fmaxf(v.w + b4.w, 0.f);
        int cq = rq & 1; int nq = mlist[rq >> 1];
        *(float4*)(x2 + (size_t)nq * (2 * HH) + cq * HH + j0) = v;
      }
    }
    __syncthreads();
  }
}

// ---- layer-3 aggregate: gather interleaved x2 rows (1KB/neighbor), unroll 4 ----
__global__ __launch_bounds__(256) void k_agg3(const float* __restrict__ x2,
    const int* __restrict__ csr, const int* __restrict__ rowptr,
    const int4* __restrict__ pack, const int* __restrict__ plist, int T,
    float* __restrict__ aggp) {
  int gt = blockIdx.x * blockDim.x + threadIdx.x;
  int w = gt >> 6, lane = gt & 63;
  int nw = (gridDim.x * blockDim.x) >> 6;
  int j4 = lane * 4;
  for (int task = w; task < T; task += nw) {
    int n = plist[task];
    int beg = rowptr[n], d = pack[n].x;
    float4 acc = make_float4(0, 0, 0, 0);
    int i = 0;
    for (; i + 4 <= d; i += 4) {
      int s0 = csr[beg + i], s1 = csr[beg + i + 1], s2 = csr[beg + i + 2], s3 = csr[beg + i + 3];
      float4 v0 = *(const float4*)(x2 + (size_t)s0 * 256 + j4);
      float4 v1 = *(const float4*)(x2 + (size_t)s1 * 256 + j4);
      float4 v2 = *(const float4*)(x2 + (size_t)s2 * 256 + j4);
      float4 v3 = *(const float4*)(x2 + (size_t)s3 * 256 + j4);
      acc.x += v0.x + v1.x + v2.x + v3.x;
      acc.y += v0.y + v1.y + v2.y + v3.y;
      acc.z += v0.z + v1.z + v2.z + v3.z;
      acc.w += v0.w + v1.w + v2.w + v3.w;
    }
    for (; i < d; i++) {
      int s0 = csr[beg + i];
      float4 v0 = *(const float4*)(x2 + (size_t)s0 * 256 + j4);
      acc.x += v0.x; acc.y += v0.y; acc.z += v0.z; acc.w += v0.w;
    }
    float inv = 1.0f / (float)max(d, 1);
    float4 o = make_float4(acc.x * inv, acc.y * inv, acc.z * inv, acc.w * inv);
    *(float4*)(aggp + (size_t)task * 256 + j4) = o;
  }
}

// ---- layer-3 GEMM fused with W0 stage: tmp0 = relu((aggp@WlT3+bl2+x2@WrT3)@W0T+b0) ----
__global__ __launch_bounds__(256) void k_gemmL3F(const float* __restrict__ Aggp,
    const float* __restrict__ x2, const float* __restrict__ WaT,
    const float* __restrict__ WxT, const float* __restrict__ W0T,
    const float* __restrict__ bias, const float* __restrict__ b0,
    const int* __restrict__ plist, float* __restrict__ tmp0) {
  __shared__ float aS[HH][36];
  __shared__ float xS[HH][36];
  int r0 = blockIdx.x << 5;
  int rr = threadIdx.x >> 3, f = threadIdx.x & 7;
  int r = r0 + rr;
  int c = r & 1; int n = plist[r >> 1];
  const float* aRow = Aggp + (size_t)r * HH;
  const float* xRow = x2 + (size_t)n * (2 * HH) + c * HH;
#pragma unroll
  for (int rep = 0; rep < 4; rep++) {
    int k0 = f * 4 + rep * 32;
    float4 av = *(const float4*)(aRow + k0);
    aS[k0 + 0][rr] = av.x; aS[k0 + 1][rr] = av.y; aS[k0 + 2][rr] = av.z; aS[k0 + 3][rr] = av.w;
    float4 xv = *(const float4*)(xRow + k0);
    xS[k0 + 0][rr] = xv.x; xS[k0 + 1][rr] = xv.y; xS[k0 + 2][rr] = xv.z; xS[k0 + 3][rr] = xv.w;
  }
  __syncthreads();
  int jg = threadIdx.x & 31, rg = threadIdx.x >> 5;
  int j0 = jg * 4;
  float4 acc[4];
  acc[0] = acc[1] = acc[2] = acc[3] = make_float4(0, 0, 0, 0);
#pragma unroll 4
  for (int k = 0; k < HH; k++) {
    float4 wx = *(const float4*)(WxT + k * HH + j0);
    float4 xv = *(const float4*)(&xS[k][rg * 4]);
    fma4(acc[0], xv.x, wx); fma4(acc[1], xv.y, wx);
    fma4(acc[2], xv.z, wx); fma4(acc[3], xv.w, wx);
    float4 wa = *(const float4*)(WaT + k * HH + j0);
    float4 av = *(const float4*)(&aS[k][rg * 4]);
    fma4(acc[0], av.x, wa); fma4(acc[1], av.y, wa);
    fma4(acc[2], av.z, wa); fma4(acc[3], av.w, wa);
  }
  float4 b4 = *(const float4*)(bias + j0);
  __syncthreads();   // all reads of aS/xS done; reuse xS for x3
#pragma unroll
  for (int q = 0; q < 4; q++) {
    xS[j0 + 0][rg * 4 + q] = acc[q].x + b4.x;
    xS[j0 + 1][rg * 4 + q] = acc[q].y + b4.y;
    xS[j0 + 2][rg * 4 + q] = acc[q].z + b4.z;
    xS[j0 + 3][rg * 4 + q] = acc[q].w + b4.w;
  }
  __syncthreads();
  float4 acc2[4];
  acc2[0] = acc2[1] = acc2[2] = acc2[3] = make_float4(0, 0, 0, 0);
#pragma unroll 4
  for (int k = 0; k < HH; k++) {
    float4 w0 = *(const float4*)(W0T + k * HH + j0);
    float4 xv = *(const float4*)(&xS[k][rg * 4]);
    fma4(acc2[0], xv.x, w0); fma4(acc2[1], xv.y, w0);
    fma4(acc2[2], xv.z, w0); fma4(acc2[3], xv.w, w0);
  }
  float4 c4 = *(const float4*)(b0 + j0);
#pragma unroll
  for (int q = 0; q < 4; q++) {
    float4 v = acc2[q];
    v.x = fmaxf(v.x + c4.x, 0.f); v.y = fmaxf(v.y + c4.y, 0.f);
    v.z = fmaxf(v.z + c4.z, 0.f); v.w = fmaxf(v.w + c4.w, 0.f);
    *(float4*)(tmp0 + (size_t)(r0 + rg * 4 + q) * HH + j0) = v;
  }
}

// ---- pair product + final MLP fused ----
__global__ __launch_bounds__(256) void k_finalP(const float* __restrict__ tmp0,
    const float* __restrict__ W1T, const float* __restrict__ b1,
    const float* __restrict__ W2, const float* __restrict__ b2,
    int P, float* __restrict__ out) {
  __shared__ float pS[2][HH];
  __shared__ float wred[4];
  int t = threadIdx.x;
  int half = t >> 7, j = t & 127;
  int i = blockIdx.x * 2 + half;
  float hs = tmp0[(size_t)(2 * i) * HH + j] + tmp0[(size_t)(2 * i + 1) * HH + j];
  float hd = tmp0[(size_t)(2 * (i + P)) * HH + j] + tmp0[(size_t)(2 * (i + P) + 1) * HH + j];
  pS[half][j] = hs * hd;
  __syncthreads();
  float acc = b1[j];
#pragma unroll 8
  for (int k = 0; k < HH; k++) acc = fmaf(pS[half][k], W1T[k * HH + j], acc);
  float v = fmaxf(acc, 0.f) * W2[j];
  for (int off = 32; off > 0; off >>= 1) v += __shfl_down(v, off);
  int wid = t >> 6, lane = t & 63;
  if (lane == 0) wred[wid] = v;
  __syncthreads();
  if (t == 0) out[i] = wred[0] + wred[1] + b2[0];
  else if (t == 128) out[i] = wred[2] + wred[3] + b2[0];
}

extern "C" void kernel_launch(void* const* d_in, const int* in_sizes, int n_in,
                              void* d_out, int out_size, void* d_ws, size_t ws_size,
                              hipStream_t stream) {
  const int* z = (const int*)d_in[0];
  const int* ei = (const int*)d_in[1];
  const float* z_table = (const float*)d_in[3];
  const float* conv_Wl = (const float*)d_in[4];
  const float* conv_bl = (const float*)d_in[5];
  const float* conv_Wr = (const float*)d_in[6];
  const float* W0 = (const float*)d_in[7];
  const float* b0 = (const float*)d_in[8];
  const float* W1 = (const float*)d_in[9];
  const float* b1 = (const float*)d_in[10];
  const float* W2 = (const float*)d_in[11];
  const float* b2 = (const float*)d_in[12];
  float* out = (float*)d_out;

  int N = in_sizes[0];
  int E = in_sizes[1] / 2;
  int P = out_size;
  int P2 = 2 * P;
  const int* srcA = ei;
  const int* dstA = ei + E;

  char* basep = (char*)d_ws;
  size_t off = 0;
  auto alloc = [&](size_t bytes) -> char* {
    off = (off + 255) & ~(size_t)255;
    char* pp = basep + off; off += bytes; return pp;
  };
  float* agg  = (float*)alloc((size_t)N * 256 * 4);
  float* x2   = (float*)alloc((size_t)N * 256 * 4);
  float* aggp = (float*)alloc((size_t)P2 * 256 * 4);
  float* tmp0 = (float*)alloc((size_t)2 * P2 * HH * 4);
  float* WT   = (float*)alloc((size_t)6 * HH * HH * 4);
  float* vecs = (float*)alloc((size_t)4 * HH * 4);
  int* zero_region = (int*)alloc((size_t)5 * N * 4);
  int* deg = zero_region;
  int* cnt = zero_region + N;
  int* mark = zero_region + 3 * (size_t)N;
  int* cursor = zero_region + 4 * (size_t)N;
  int* rowptr = (int*)alloc((size_t)N * 4);
  int* mlist = (int*)alloc((size_t)N * 4);
  int* plist = (int*)alloc((size_t)P2 * 4);
  int* csr = (int*)alloc((size_t)E * 4);
  ull* locout = (ull*)alloc((size_t)N * 8);
  ull* partials = (ull*)alloc(64 * 8);
  int* Rm_dev = (int*)alloc(4);
  int4* pack = (int4*)alloc((size_t)N * 16);
  (void)ws_size; (void)n_in;

  hipMemsetAsync(zero_region, 0, (size_t)5 * N * 4, stream);
  int nT = (6 * HH * HH + 255) / 256;
  k_prep<<<nT + 1, 256, 0, stream>>>(conv_Wl, conv_Wr, W0, W1, z_table, WT, vecs, nT);
  k_edge<<<2048, 256, 0, stream>>>(z, srcA, dstA, N, E, deg, cnt, mark);
  int nb = (N + 1023) / 1024;
  k_scan1<<<nb, 256, 0, stream>>>(deg, mark, z, N, locout, partials);
  k_post<<<(N + 255) / 256, 256, 0, stream>>>(locout, partials, z, mark, deg, cnt, N, P,
                                              rowptr, mlist, plist, Rm_dev, pack);
  k_csr<<<(E + 255) / 256, 256, 0, stream>>>(srcA, dstA, E, rowptr, cursor, csr);
  k_agg2<<<2048, 256, 0, stream>>>(pack, vecs, conv_bl, csr, rowptr, mlist, Rm_dev, agg);
  k_gemmL2<<<1536, 256, 0, stream>>>(agg, pack, vecs, WT, WT + HH * HH, conv_bl + HH,
                                     conv_bl, mlist, Rm_dev, x2);
  k_agg3<<<512, 256, 0, stream>>>(x2, csr, rowptr, pack, plist, P2, aggp);
  k_gemmL3F<<<(2 * P2) / 32, 256, 0, stream>>>(aggp, x2, WT + 2 * HH * HH, WT + 3 * HH * HH,
                                               WT + 4 * HH * HH, conv_bl + 2 * HH, b0, plist, tmp0);
  k_finalP<<<P / 2, 256, 0, stream>>>(tmp0, WT + 5 * HH * HH, b1, W2, b2, P, out);
}

// Round 3
// 157.879 us; speedup vs baseline: 1.8123x; 1.4974x over previous
//
#include <hip/hip_runtime.h>
#include <stdint.h>

#define HH 128
#define DMAXT 64
#define CMAXT 8
typedef unsigned long long ull;

__device__ __forceinline__ ull shfl_up64(ull v, int d) {
  unsigned lo = (unsigned)__shfl_up((int)(unsigned)(v & 0xffffffffULL), d);
  unsigned hi = (unsigned)__shfl_up((int)(unsigned)(v >> 32), d);
  return ((ull)hi << 32) | (ull)lo;
}
__device__ __forceinline__ ull shfl_down64(ull v, int d) {
  unsigned lo = (unsigned)__shfl_down((int)(unsigned)(v & 0xffffffffULL), d);
  unsigned hi = (unsigned)__shfl_down((int)(unsigned)(v >> 32), d);
  return ((ull)hi << 32) | (ull)lo;
}

// ---- weights transpose (6 mats) + layer-1 basis vectors ----
__global__ void k_prep(const float* __restrict__ Wl, const float* __restrict__ Wr,
                       const float* __restrict__ W0, const float* __restrict__ W1,
                       const float* __restrict__ zt, float* __restrict__ WT,
                       float* __restrict__ vecs, int nTblk) {
  if ((int)blockIdx.x == nTblk) {
    int j = threadIdx.x;
    if (j >= HH) return;
    float a0 = 0, a1 = 0, r0 = 0, r1 = 0;
    for (int k = 0; k < HH; k++) {
      float z0 = zt[k], z1 = zt[HH + k];
      float wl = Wl[j * HH + k], wr = Wr[j * HH + k];
      a0 += z0 * wl; a1 += z1 * wl; r0 += z0 * wr; r1 += z1 * wr;
    }
    vecs[j] = a0; vecs[HH + j] = a1; vecs[2 * HH + j] = r0; vecs[3 * HH + j] = r1;
    return;
  }
  int gid = blockIdx.x * blockDim.x + threadIdx.x;
  if (gid >= 6 * HH * HH) return;
  int m = gid / (HH * HH);
  int idx = gid % (HH * HH);
  int k = idx / HH, j = idx % HH;
  const float* src;
  switch (m) {
    case 0: src = Wl + 1 * HH * HH; break;   // WlT2
    case 1: src = Wr + 1 * HH * HH; break;   // WrT2
    case 2: src = Wl + 2 * HH * HH; break;   // WlT3
    case 3: src = Wr + 2 * HH * HH; break;   // WrT3
    case 4: src = W0; break;                 // W0T
    default: src = W1; break;                // W1T
  }
  WT[gid] = src[j * HH + k];
}

// ---- edge pass: single 64-bit atomic packs deg | cnt1 | cnt2; mark set ----
__global__ void k_edge(const int* __restrict__ z, const int* __restrict__ src,
                       const int* __restrict__ dst, int N, int E,
                       ull* __restrict__ cnt64, int* __restrict__ mark) {
  int tid = blockIdx.x * blockDim.x + threadIdx.x;
  int stride = gridDim.x * blockDim.x;
  for (int n = tid; n < N; n += stride)
    if (z[n] <= 2) mark[n] = 1;
  for (int e = tid; e < E; e += stride) {
    int s = src[e], d = dst[e];
    int zs = z[s];
    ull val = 1ULL | ((ull)(zs == 1) << 20) | ((ull)(zs == 2) << 40);
    atomicAdd(&cnt64[d], val);
    if (z[d] <= 2) mark[s] = 1;
  }
}

// ---- packed 64-bit scan: deg(0..19) | mark(20..39) | z==1(40..51) | z==2(52..63) ----
__global__ void k_scan1(const ull* __restrict__ cnt64, const int* __restrict__ mark,
                        const int* __restrict__ z, int N,
                        ull* __restrict__ locout, ull* __restrict__ partials) {
  __shared__ ull wsum[4];
  int t = threadIdx.x, b = blockIdx.x;
  int base = b * 1024 + t * 4;
  ull l[4]; ull s = 0;
  for (int i = 0; i < 4; i++) {
    int idx = base + i; ull v = 0;
    if (idx < N) {
      int zz = z[idx];
      v = (cnt64[idx] & 0xFFFFFULL) | ((ull)mark[idx] << 20)
        | ((ull)(zz == 1) << 40) | ((ull)(zz == 2) << 52);
    }
    l[i] = s; s += v;
  }
  int lane = t & 63, wid = t >> 6;
  ull vi = s;
  for (int d2 = 1; d2 < 64; d2 <<= 1) { ull o = shfl_up64(vi, d2); if (lane >= d2) vi += o; }
  if (lane == 63) wsum[wid] = vi;
  __syncthreads();
  ull woff = 0;
  for (int w = 0; w < wid; w++) woff += wsum[w];
  ull thrbase = woff + vi - s;
  for (int i = 0; i < 4; i++) {
    int idx = base + i;
    if (idx < N) locout[idx] = thrbase + l[i];
  }
  if (t == 255) partials[b] = woff + vi;
}

// ---- consume scan: rowptr, mlist, minv, plist, pack ----
__global__ __launch_bounds__(256) void k_post(const ull* __restrict__ locout, const ull* __restrict__ partials,
                       const int* __restrict__ z, const int* __restrict__ mark,
                       const ull* __restrict__ cnt64,
                       int N, int P, int* __restrict__ rowptr, int* __restrict__ mlist,
                       int* __restrict__ minv, int* __restrict__ plist,
                       int* __restrict__ Rm, int4* __restrict__ pack) {
  __shared__ ull base_s;
  int t = threadIdx.x;
  if (t < 64) {
    int need = blockIdx.x >> 2;
    ull v = (t < need) ? partials[t] : 0ULL;
    for (int o = 32; o > 0; o >>= 1) v += shfl_down64(v, o);
    if (t == 0) base_s = v;
  }
  __syncthreads();
  int n = blockIdx.x * 256 + t;
  if (n >= N) return;
  ull s = locout[n] + base_s;
  int rp = (int)(s & 0xFFFFF);
  int mp = (int)((s >> 20) & 0xFFFFF);
  int r1 = (int)((s >> 40) & 0xFFF);
  int r2 = (int)(s >> 52);
  rowptr[n] = rp;
  if (mark[n]) { mlist[mp] = n; minv[n] = mp; }
  int zz = z[n];
  if (zz == 1) plist[r1] = n;
  else if (zz == 2) plist[P + r2] = n;
  ull cv = cnt64[n];
  pack[n] = make_int4((int)(cv & 0xFFFFF), (int)((cv >> 20) & 0xFFFFF),
                      (int)((cv >> 40) & 0xFFFFF), zz);
  if (n == N - 1) *Rm = mp + mark[n];
}

__global__ void k_csr(const int* __restrict__ src, const int* __restrict__ dst, int E,
                      const int* __restrict__ rowptr, int* __restrict__ cursor,
                      int* __restrict__ csr_src) {
  int e = blockIdx.x * blockDim.x + threadIdx.x;
  if (e >= E) return;
  int d = dst[e];
  int pos = atomicAdd(&cursor[d], 1);
  csr_src[rowptr[d] + pos] = src[e];
}

// ---- build y-tables: y_l[v] = x1_v @ WlT2 ; y_rb[v] = x1_v @ WrT2 + bl1 ----
// v = ((d*8 + cnt)*2 + sel), d<64, cnt<8, sel in {0,1}
__global__ __launch_bounds__(256) void k_ytab(const float* __restrict__ vecs,
    const float* __restrict__ bl0, const float* __restrict__ bl1,
    const float* __restrict__ WlT2, const float* __restrict__ WrT2,
    float* __restrict__ y_l, float* __restrict__ y_rb) {
  __shared__ float xS[2][HH];
  int t = threadIdx.x, half = t >> 7, j = t & 127;
  int v = blockIdx.x * 2 + half;
  int d = v >> 4, cnt = (v >> 1) & 7, sel = v & 1;
  float invd = 1.0f / (float)max(d, 1);
  float u1 = (float)cnt * invd, u0 = (float)(d - cnt) * invd;
  xS[half][j] = fmaxf(fmaf(u0, vecs[j], fmaf(u1, vecs[HH + j],
                     bl0[j] + vecs[(2 + sel) * HH + j])), 0.f);
  __syncthreads();
  float al = 0.f, ar = 0.f;
#pragma unroll 8
  for (int k = 0; k < HH; k++) {
    float x = xS[half][k];
    al = fmaf(x, WlT2[k * HH + j], al);
    ar = fmaf(x, WrT2[k * HH + j], ar);
  }
  y_l[(size_t)v * HH + j] = al;
  y_rb[(size_t)v * HH + j] = ar + bl1[j];
}

// ---- exact fallback for d>=64 or cnt>=8: y row computed on the fly ----
__device__ __noinline__ float4 yrow_fb(const float* __restrict__ vecs,
    const float* __restrict__ bl0, const float* __restrict__ WTm,
    int j4, int d, int cnt, int sel) {
  float invd = 1.0f / (float)max(d, 1);
  float u1 = (float)cnt * invd, u0 = (float)(d - cnt) * invd;
  const float* Rv = vecs + (2 + sel) * HH;
  float4 acc = make_float4(0, 0, 0, 0);
  for (int k = 0; k < HH; k++) {
    float x = fmaxf(fmaf(u0, vecs[k], fmaf(u1, vecs[HH + k], bl0[k] + Rv[k])), 0.f);
    float4 wv = *(const float4*)(WTm + k * HH + j4);
    acc.x = fmaf(x, wv.x, acc.x); acc.y = fmaf(x, wv.y, acc.y);
    acc.z = fmaf(x, wv.z, acc.z); acc.w = fmaf(x, wv.w, acc.w);
  }
  return acc;
}

__device__ __forceinline__ float4 yl_row(int4 p, int ch, int zc, int j4,
    const float* __restrict__ y_l, const float* __restrict__ vecs,
    const float* __restrict__ bl0, const float* __restrict__ WlT2) {
  int cc = ch ? p.z : p.y;
  int sel = (p.w == zc) ? 1 : 0;
  if (p.x < DMAXT && cc < CMAXT)
    return *(const float4*)(y_l + (size_t)((((p.x << 3) + cc) << 1) + sel) * HH + j4);
  return yrow_fb(vecs, bl0, WlT2, j4, p.x, cc, sel);
}

// ---- layer-2: x2c[task] = relu(mean_s y_l[v(s)] + y_rb[v(n)]) ----
__global__ __launch_bounds__(256) void k_agg2Y(const int4* __restrict__ pack,
    const float* __restrict__ y_l, const float* __restrict__ y_rb,
    const float* __restrict__ vecs, const float* __restrict__ bl0,
    const float* __restrict__ WlT2, const float* __restrict__ WrT2,
    const float* __restrict__ bl1,
    const int* __restrict__ csr, const int* __restrict__ rowptr,
    const int* __restrict__ mlist, const int* __restrict__ Rdev,
    float* __restrict__ x2c) {
  int gt = blockIdx.x * blockDim.x + threadIdx.x;
  int w = gt >> 6, lane = gt & 63;
  int nw = (gridDim.x * blockDim.x) >> 6;
  int T = *Rdev;
  int ch = lane >> 5, j4 = (lane & 31) * 4;
  int zc = ch + 1;
  for (int task = w; task < T; task += nw) {
    int n = mlist[task];
    int4 pn = pack[n];
    int beg = rowptr[n], d = pn.x;
    float4 acc = make_float4(0, 0, 0, 0);
    int i = 0;
    for (; i + 2 <= d; i += 2) {
      int s0 = csr[beg + i], s1 = csr[beg + i + 1];
      int4 p0 = pack[s0], p1 = pack[s1];
      float4 v0 = yl_row(p0, ch, zc, j4, y_l, vecs, bl0, WlT2);
      float4 v1 = yl_row(p1, ch, zc, j4, y_l, vecs, bl0, WlT2);
      acc.x += v0.x + v1.x; acc.y += v0.y + v1.y;
      acc.z += v0.z + v1.z; acc.w += v0.w + v1.w;
    }
    if (i < d) {
      int4 p0 = pack[csr[beg + i]];
      float4 v0 = yl_row(p0, ch, zc, j4, y_l, vecs, bl0, WlT2);
      acc.x += v0.x; acc.y += v0.y; acc.z += v0.z; acc.w += v0.w;
    }
    float inv = 1.0f / (float)max(d, 1);
    // self term
    int ccn = ch ? pn.z : pn.y;
    int seln = (pn.w == zc) ? 1 : 0;
    float4 yr;
    if (pn.x < DMAXT && ccn < CMAXT) {
      yr = *(const float4*)(y_rb + (size_t)((((pn.x << 3) + ccn) << 1) + seln) * HH + j4);
    } else {
      yr = yrow_fb(vecs, bl0, WrT2, j4, pn.x, ccn, seln);
      float4 bb = *(const float4*)(bl1 + j4);
      yr.x += bb.x; yr.y += bb.y; yr.z += bb.z; yr.w += bb.w;
    }
    float4 o;
    o.x = fmaxf(fmaf(acc.x, inv, yr.x), 0.f);
    o.y = fmaxf(fmaf(acc.y, inv, yr.y), 0.f);
    o.z = fmaxf(fmaf(acc.z, inv, yr.z), 0.f);
    o.w = fmaxf(fmaf(acc.w, inv, yr.w), 0.f);
    *(float4*)(x2c + (size_t)task * 256 + ch * HH + j4) = o;
  }
}

// ---- layer-3 aggregate: gather compact x2c rows via minv ----
__global__ __launch_bounds__(256) void k_agg3(const float* __restrict__ x2c,
    const int* __restrict__ csr, const int* __restrict__ rowptr,
    const int4* __restrict__ pack, const int* __restrict__ plist,
    const int* __restrict__ minv, int T, float* __restrict__ aggp) {
  int gt = blockIdx.x * blockDim.x + threadIdx.x;
  int w = gt >> 6, lane = gt & 63;
  int nw = (gridDim.x * blockDim.x) >> 6;
  int j4 = lane * 4;
  for (int task = w; task < T; task += nw) {
    int n = plist[task];
    int beg = rowptr[n], d = pack[n].x;
    float4 acc = make_float4(0, 0, 0, 0);
    int i = 0;
    for (; i + 4 <= d; i += 4) {
      int m0 = minv[csr[beg + i]], m1 = minv[csr[beg + i + 1]];
      int m2 = minv[csr[beg + i + 2]], m3 = minv[csr[beg + i + 3]];
      float4 v0 = *(const float4*)(x2c + (size_t)m0 * 256 + j4);
      float4 v1 = *(const float4*)(x2c + (size_t)m1 * 256 + j4);
      float4 v2 = *(const float4*)(x2c + (size_t)m2 * 256 + j4);
      float4 v3 = *(const float4*)(x2c + (size_t)m3 * 256 + j4);
      acc.x += v0.x + v1.x + v2.x + v3.x;
      acc.y += v0.y + v1.y + v2.y + v3.y;
      acc.z += v0.z + v1.z + v2.z + v3.z;
      acc.w += v0.w + v1.w + v2.w + v3.w;
    }
    for (; i < d; i++) {
      int m0 = minv[csr[beg + i]];
      float4 v0 = *(const float4*)(x2c + (size_t)m0 * 256 + j4);
      acc.x += v0.x; acc.y += v0.y; acc.z += v0.z; acc.w += v0.w;
    }
    float inv = 1.0f / (float)max(d, 1);
    float4 o = make_float4(acc.x * inv, acc.y * inv, acc.z * inv, acc.w * inv);
    *(float4*)(aggp + (size_t)task * 256 + j4) = o;
  }
}

// ---- layer-3 + W0 fused, column-parallel: 2 rows per block ----
__global__ __launch_bounds__(256) void k_gemmL3F(const float* __restrict__ aggp,
    const float* __restrict__ x2c, const float* __restrict__ WlT3,
    const float* __restrict__ WrT3, const float* __restrict__ W0T,
    const float* __restrict__ bl2, const float* __restrict__ b0,
    const int* __restrict__ plist, const int* __restrict__ minv,
    float* __restrict__ tmp0) {
  __shared__ float aS[2][HH], xS[2][HH], x3S[2][HH];
  int t = threadIdx.x, half = t >> 7, j = t & 127;
  int r = blockIdx.x * 2 + half;
  int c = r & 1, i = r >> 1;
  int n = plist[i], m = minv[n];
  aS[half][j] = aggp[(size_t)i * 256 + c * HH + j];
  xS[half][j] = x2c[(size_t)m * 256 + c * HH + j];
  __syncthreads();
  float acc = bl2[j];
#pragma unroll 4
  for (int k = 0; k < HH; k++)
    acc = fmaf(aS[half][k], WlT3[k * HH + j], fmaf(xS[half][k], WrT3[k * HH + j], acc));
  x3S[half][j] = acc;
  __syncthreads();
  float acc2 = b0[j];
#pragma unroll 8
  for (int k = 0; k < HH; k++) acc2 = fmaf(x3S[half][k], W0T[k * HH + j], acc2);
  tmp0[(size_t)r * HH + j] = fmaxf(acc2, 0.f);
}

// ---- pair product + final MLP fused ----
__global__ __launch_bounds__(256) void k_finalP(const float* __restrict__ tmp0,
    const float* __restrict__ W1T, const float* __restrict__ b1,
    const float* __restrict__ W2, const float* __restrict__ b2,
    int P, float* __restrict__ out) {
  __shared__ float pS[2][HH];
  __shared__ float wred[4];
  int t = threadIdx.x;
  int half = t >> 7, j = t & 127;
  int i = blockIdx.x * 2 + half;
  float hs = tmp0[(size_t)(2 * i) * HH + j] + tmp0[(size_t)(2 * i + 1) * HH + j];
  float hd = tmp0[(size_t)(2 * (i + P)) * HH + j] + tmp0[(size_t)(2 * (i + P) + 1) * HH + j];
  pS[half][j] = hs * hd;
  __syncthreads();
  float acc = b1[j];
#pragma unroll 8
  for (int k = 0; k < HH; k++) acc = fmaf(pS[half][k], W1T[k * HH + j], acc);
  float v = fmaxf(acc, 0.f) * W2[j];
  for (int off = 32; off > 0; off >>= 1) v += __shfl_down(v, off);
  int wid = t >> 6, lane = t & 63;
  if (lane == 0) wred[wid] = v;
  __syncthreads();
  if (t == 0) out[i] = wred[0] + wred[1] + b2[0];
  else if (t == 128) out[i] = wred[2] + wred[3] + b2[0];
}

extern "C" void kernel_launch(void* const* d_in, const int* in_sizes, int n_in,
                              void* d_out, int out_size, void* d_ws, size_t ws_size,
                              hipStream_t stream) {
  const int* z = (const int*)d_in[0];
  const int* ei = (const int*)d_in[1];
  const float* z_table = (const float*)d_in[3];
  const float* conv_Wl = (const float*)d_in[4];
  const float* conv_bl = (const float*)d_in[5];
  const float* conv_Wr = (const float*)d_in[6];
  const float* W0 = (const float*)d_in[7];
  const float* b0 = (const float*)d_in[8];
  const float* W1 = (const float*)d_in[9];
  const float* b1 = (const float*)d_in[10];
  const float* W2 = (const float*)d_in[11];
  const float* b2 = (const float*)d_in[12];
  float* out = (float*)d_out;

  int N = in_sizes[0];
  int E = in_sizes[1] / 2;
  int P = out_size;
  int P2 = 2 * P;
  const int* srcA = ei;
  const int* dstA = ei + E;

  char* basep = (char*)d_ws;
  size_t off = 0;
  auto alloc = [&](size_t bytes) -> char* {
    off = (off + 255) & ~(size_t)255;
    char* pp = basep + off; off += bytes; return pp;
  };
  float* WT   = (float*)alloc((size_t)6 * HH * HH * 4);
  float* vecs = (float*)alloc((size_t)4 * HH * 4);
  float* y_l  = (float*)alloc((size_t)1024 * HH * 4);
  float* y_rb = (float*)alloc((size_t)1024 * HH * 4);
  float* x2c  = (float*)alloc((size_t)N * 256 * 4);
  float* aggp = (float*)alloc((size_t)P2 * 256 * 4);
  float* tmp0 = (float*)alloc((size_t)2 * P2 * HH * 4);
  char* zr    = alloc((size_t)16 * N);
  ull* cnt64  = (ull*)zr;
  int* mark   = (int*)(zr + (size_t)8 * N);
  int* cursor = (int*)(zr + (size_t)12 * N);
  int* rowptr = (int*)alloc((size_t)N * 4);
  int* mlist  = (int*)alloc((size_t)N * 4);
  int* minv   = (int*)alloc((size_t)N * 4);
  int* plist  = (int*)alloc((size_t)P2 * 4);
  int* csr    = (int*)alloc((size_t)E * 4);
  ull* locout = (ull*)alloc((size_t)N * 8);
  ull* partials = (ull*)alloc(64 * 8);
  int* Rm_dev = (int*)alloc(4);
  int4* pack  = (int4*)alloc((size_t)N * 16);
  (void)ws_size; (void)n_in;

  hipMemsetAsync(zr, 0, (size_t)16 * N, stream);
  int nT = (6 * HH * HH + 255) / 256;
  k_prep<<<nT + 1, 256, 0, stream>>>(conv_Wl, conv_Wr, W0, W1, z_table, WT, vecs, nT);
  k_edge<<<2048, 256, 0, stream>>>(z, srcA, dstA, N, E, cnt64, mark);
  int nb = (N + 1023) / 1024;
  k_scan1<<<nb, 256, 0, stream>>>(cnt64, mark, z, N, locout, partials);
  k_post<<<(N + 255) / 256, 256, 0, stream>>>(locout, partials, z, mark, cnt64, N, P,
                                              rowptr, mlist, minv, plist, Rm_dev, pack);
  k_csr<<<(E + 255) / 256, 256, 0, stream>>>(srcA, dstA, E, rowptr, cursor, csr);
  k_ytab<<<512, 256, 0, stream>>>(vecs, conv_bl, conv_bl + HH, WT, WT + HH * HH, y_l, y_rb);
  k_agg2Y<<<2048, 256, 0, stream>>>(pack, y_l, y_rb, vecs, conv_bl, WT, WT + HH * HH,
                                    conv_bl + HH, csr, rowptr, mlist, Rm_dev, x2c);
  k_agg3<<<512, 256, 0, stream>>>(x2c, csr, rowptr, pack, plist, minv, P2, aggp);
  k_gemmL3F<<<P2, 256, 0, stream>>>(aggp, x2c, WT + 2 * HH * HH, WT + 3 * HH * HH,
                                    WT + 4 * HH * HH, conv_bl + 2 * HH, b0, plist, minv, tmp0);
  k_finalP<<<P / 2, 256, 0, stream>>>(tmp0, WT + 5 * HH * HH, b1, W2, b2, P, out);
}